// Round 2
// baseline (195.069 us; speedup 1.0000x reference)
//
#include <hip/hip_runtime.h>

// ---------------------------------------------------------------------------
// ContrastiveLoss: loss = mean_i [ 0.5*(LSE_row_i + LSE_col_i) - diag_i ]
// over logits = normalize(img) @ normalize(txt)^T / 0.07, N=8192, D=1024.
// |logit| <= 14.29 -> exp() safe in fp32, no max subtraction needed.
//
// R16 = R15 geometry (256x256, 8 waves 2x4, dbuf 128KB LDS, zero-conflict
// chunk-interleave) + the TRUE 8-phase fine-grained schedule (m198/m201):
// per K-tile, 4 phases = one C-quadrant each:
//   {ds_read af pair (+bg at p0); issue phase's staging gloads;
//    s_barrier; lgkmcnt(0); setprio(1); 8 MFMA; setprio(0); s_barrier}
// R15's coarse split (all reads up front, stage at tile end, 2 barriers)
// was NULL (102->100.7us, MfmaUtil 28%) - exactly m196's measured result.
// Region-ownership staging: phase p reads A rows p*32+[0,32) u 128+p*32+
// [0,32) ("region p"); overwrite gloads for region p issue in phase p+1
// (after the trailing barrier that proves all waves consumed it). B is read
// only in p0 -> B gloads issue in p1. A-staging remapped so each wave owns
// one 1KB chunk per region (wave w: rows (w&1)*16+((w&2)?128:0)+[0,16),
// window w>>2); region 3 of tile t+1 issues at tile t phase 0 into buf^1.
// Uniform per-wave vmcnt ledger, issue order per tile:
//   [Ar3(t+1)]@p0  [B*4 + Ar0(t+2)]@p1  [Ar1(t+2)]@p2  [Ar2(t+2)]@p3
// -> vmcnt(7) at every p3 retires stage(t+1) exactly, keeps stage(t+2)'s 7
// in flight (never drained); vmcnt(0) only at t=NT-2. Prologue stages tiles
// 0,1 fully (16 gloads) then vmcnt(8)+barrier.
// Carried: R7/R10 producer chunk interleave -> 0 bank conflicts on b128;
// R13 inverted XCD swizzle; R4/R1 staging/read swizzle identities
// ((row>>1)&3 invariant under +16/+32/+128 row offsets).
// ---------------------------------------------------------------------------

#define BM 256
#define BN 256
#define BKB 128   // fp8 K-bytes per iteration (one MFMA k-step)

typedef float floatx4 __attribute__((ext_vector_type(4)));
typedef int   intx4   __attribute__((ext_vector_type(4)));
typedef int   intx8   __attribute__((ext_vector_type(8)));

__device__ __forceinline__ void gload_lds16(const unsigned char* g, unsigned char* lds) {
    __builtin_amdgcn_global_load_lds(
        (const __attribute__((address_space(1))) void*)g,
        (__attribute__((address_space(3))) void*)lds,
        16, 0, 0);
}

// ---- Kernel 1: row L2-normalize, x16, fp32 -> fp8 e4m3, chunk-interleaved --
__global__ __launch_bounds__(256)
void normalize_fp8(const float* __restrict__ img, const float* __restrict__ txt,
                   unsigned int* __restrict__ oimg, unsigned int* __restrict__ otxt,
                   float* __restrict__ sums, float* __restrict__ out, int N) {
    const int gi = blockIdx.x * 256 + threadIdx.x;
    if (gi < 2 * N) sums[gi] = 0.f;
    if (gi == 0) out[0] = 0.f;

    const int gw = blockIdx.x * 4 + (threadIdx.x >> 6);   // row id in [0,2N)
    const int lane = threadIdx.x & 63;
    const float* in = (gw < N) ? img : txt;
    unsigned int* o = (gw < N) ? oimg : otxt;
    const int row = (gw < N) ? gw : gw - N;
    const float4* rp = (const float4*)(in + (size_t)row * 1024);

    float4 v[4];
    float ss = 0.f;
    #pragma unroll
    for (int j = 0; j < 4; ++j) {
        v[j] = rp[j * 64 + lane];
        ss += v[j].x * v[j].x + v[j].y * v[j].y + v[j].z * v[j].z + v[j].w * v[j].w;
    }
    #pragma unroll
    for (int o2 = 1; o2 < 64; o2 <<= 1) ss += __shfl_xor(ss, o2);
    const float inv = 16.0f / fmaxf(sqrtf(ss), 1e-8f);   // x16 quantization scale
    #pragma unroll
    for (int j = 0; j < 4; ++j) {
        int p = __builtin_amdgcn_cvt_pk_fp8_f32(v[j].x * inv, v[j].y * inv, 0, false);
        p = __builtin_amdgcn_cvt_pk_fp8_f32(v[j].z * inv, v[j].w * inv, p, true);
        const int d = j * 64 + lane;
        const int c = (d >> 2) & 7;
        const int pp = (c & 1) * 4 + (c >> 1);
        const int dp = (d & ~31) | (pp * 4 + (d & 3));
        o[(size_t)row * 256 + dp] = (unsigned int)p;
    }
}

// ---- Kernel 2: 256x256-tile NT MX-fp8 GEMM + fused exp/row-col sums/diag ---
__global__ __launch_bounds__(512, 2)
void gemm_exp_kernel(const unsigned char* __restrict__ A,   // img_q [N][K] fp8 (interleaved)
                     const unsigned char* __restrict__ B,   // txt_q [N][K] fp8 (interleaved)
                     float* __restrict__ rowsum, float* __restrict__ colsum,
                     float* __restrict__ diag, int K, float scale) {
    // XCD-inverted swizzle: xcd = id&7 owns bm strip [xcd*4, xcd*4+4).
    const int id = blockIdx.x;
    const int idp = id >> 3;
    const int bm = (id & 7) * 4 + (idp & 3);
    const int bn = idp >> 2;

    // LDS layout per matrix: [buf:32768][win:16384][row:64][slot:16];
    // slot s of row r holds global chunk s ^ ((r>>1)&3) of that window.
    __shared__ unsigned char As[2 * 2 * 256 * 64];   // 64 KB
    __shared__ unsigned char Bs[2 * 2 * 256 * 64];   // 64 KB

    const int tid = threadIdx.x;
    const int lane = tid & 63;
    const int wave = tid >> 6;           // 0..7
    const int quad = lane >> 4;
    const int lanelo = lane & 15;
    const int wrow = (wave >> 2) * 128;  // output row strip
    const int wcol = (wave & 3) * 64;    // output col strip

    floatx4 acc[8][4] = {};

    // ---- B staging (per thread: rows tid>>2 and +128, 2 windows; 4 gloads) --
    const int r0 = tid >> 2;
    const int kg0 = ((tid & 3) ^ ((r0 >> 1) & 3)) * 16;   // +128 row: same xor
    const unsigned char* pb0 = B + ((size_t)bn * BN + r0) * K + kg0;
    const unsigned char* pb1 = pb0 + (size_t)128 * K;
    unsigned char* ldsB = Bs + tid * 16;   // +8192 row+128, +16384 win1

    // ---- A staging (per wave: one 16-row chunk per region j; 4 gloads) ------
    const int wndA = wave >> 2;
    const int rowOffA = (wave & 1) * 16 + ((wave & 2) ? 128 : 0) + (lane >> 2);
    const int slotA = lane & 3;
    const int kgA = ((slotA ^ ((rowOffA >> 1) & 3)) * 16) + wndA * 64;  // j*32 doesn't change xor
    const unsigned char* pa = A + ((size_t)bm * BM + rowOffA) * K + kgA;
    unsigned char* ldsA = As + wndA * 16384 + rowOffA * 64 + slotA * 16; // = base + lane*16

    // ---- fragment read offsets (R15 geometry; ((row>>1)&3)==((lanelo>>1)&3))
    const int swx = (quad ^ ((lanelo >> 1) & 3)) * 16;
    const int aoffB = (wrow + lanelo) * 64 + swx;
    const int boffB = (wcol + lanelo) * 64 + swx;

    const int NT = K >> 7;               // 8 K-tiles

    // ---- prologue: stage tiles 0 and 1 fully (8 gloads each) ----
    #pragma unroll
    for (int t = 0; t < 2; ++t) {
        const int k = t * BKB;
        const int bo = t * 32768;
        gload_lds16(pb0 + k,      ldsB + bo);
        gload_lds16(pb0 + k + 64, ldsB + bo + 16384);
        gload_lds16(pb1 + k,      ldsB + bo + 8192);
        gload_lds16(pb1 + k + 64, ldsB + bo + 8192 + 16384);
        #pragma unroll
        for (int j = 0; j < 4; ++j)
            gload_lds16(pa + (size_t)(j * 32) * K + k, ldsA + bo + j * 2048);
    }
    asm volatile("s_waitcnt vmcnt(8)" ::: "memory");   // stage(0) landed
    __builtin_amdgcn_s_barrier();

    for (int t = 0; t < NT; ++t) {
        const int buf = t & 1;
        const unsigned char* Ab = As + buf * 32768;
        const unsigned char* Bb = Bs + buf * 32768;
        const int bo2 = buf * 32768;          // stage(t+2) dest
        const int bo1 = (buf ^ 1) * 32768;    // Ar3(t+1) dest
        const int k1 = (t + 1) * BKB;
        const int k2 = (t + 2) * BKB;

        intx8 bg[4];
        #pragma unroll
        for (int p = 0; p < 4; ++p) {
            // ---- ds reads for this phase (issued pre-barrier) ----
            if (p == 0) {
                #pragma unroll
                for (int tn = 0; tn < 4; ++tn) {
                    const intx4 blo = *(const intx4*)(Bb + boffB + tn * 1024);
                    const intx4 bhi = *(const intx4*)(Bb + 16384 + boffB + tn * 1024);
                    bg[tn] = __builtin_shufflevector(blo, bhi, 0, 1, 2, 3, 4, 5, 6, 7);
                }
            }
            intx8 af[2];
            #pragma unroll
            for (int u = 0; u < 2; ++u) {
                const int tm = p * 2 + u;
                const intx4 alo = *(const intx4*)(Ab + aoffB + tm * 1024);
                const intx4 ahi = *(const intx4*)(Ab + 16384 + aoffB + tm * 1024);
                af[u] = __builtin_shufflevector(alo, ahi, 0, 1, 2, 3, 4, 5, 6, 7);
            }

            // ---- staging issues for this phase (region freed last phase) ----
            if (p == 0) {
                if (t >= 1 && t + 1 < NT)      // A region 3 of tile t+1 -> buf^1
                    gload_lds16(pa + (size_t)(3 * 32) * K + k1, ldsA + bo1 + 3 * 2048);
            } else if (p == 1) {
                if (t + 2 < NT) {              // B (freed after p0) + A region 0
                    gload_lds16(pb0 + k2,      ldsB + bo2);
                    gload_lds16(pb0 + k2 + 64, ldsB + bo2 + 16384);
                    gload_lds16(pb1 + k2,      ldsB + bo2 + 8192);
                    gload_lds16(pb1 + k2 + 64, ldsB + bo2 + 8192 + 16384);
                    gload_lds16(pa + k2,       ldsA + bo2);
                }
            } else if (p == 2) {
                if (t + 2 < NT)                // A region 1
                    gload_lds16(pa + (size_t)(1 * 32) * K + k2, ldsA + bo2 + 1 * 2048);
            } else {                           // p == 3
                if (t + 2 < NT)                // A region 2
                    gload_lds16(pa + (size_t)(2 * 32) * K + k2, ldsA + bo2 + 2 * 2048);
                // Counted wait: retire stage(t+1) exactly (7 newer = stage(t+2) so far).
                if (t < NT - 2)       { asm volatile("s_waitcnt vmcnt(7)" ::: "memory"); }
                else if (t == NT - 2) { asm volatile("s_waitcnt vmcnt(0)" ::: "memory"); }
            }

            __builtin_amdgcn_s_barrier();                       // phase data published
            asm volatile("s_waitcnt lgkmcnt(0)" ::: "memory");  // own reads complete
            __builtin_amdgcn_s_setprio(1);
            #pragma unroll
            for (int u = 0; u < 2; ++u)
                #pragma unroll
                for (int tn = 0; tn < 4; ++tn)
                    acc[p * 2 + u][tn] = __builtin_amdgcn_mfma_scale_f32_16x16x128_f8f6f4(
                        af[u], bg[tn], acc[p * 2 + u][tn],
                        0, 0,          // cbsz = fp8 e4m3, blgp = fp8 e4m3
                        0, 127,        // A scale: 1.0
                        0, 127);       // B scale: 1.0
            __builtin_amdgcn_s_setprio(0);
            __builtin_amdgcn_s_barrier();                       // phase reads consumed
        }
    }

    // ---- epilogue: scale, capture diag, exp in place ----
    const int growb = bm * BM + wrow;
    const int gcolb = bn * BN + wcol;

    #pragma unroll
    for (int tm = 0; tm < 8; ++tm)
        #pragma unroll
        for (int tn = 0; tn < 4; ++tn)
            #pragma unroll
            for (int r = 0; r < 4; ++r) {
                const float l = acc[tm][tn][r] * scale;
                const int grow = growb + tm * 16 + quad * 4 + r;
                const int gcol = gcolb + tn * 16 + lanelo;
                if (grow == gcol) diag[grow] = l;
                acc[tm][tn][r] = __expf(l);
            }

    // ---- row sums: reduce over the 16 lanes sharing a row, then atomicAdd ----
    #pragma unroll
    for (int tm = 0; tm < 8; ++tm) {
        floatx4 rs = acc[tm][0] + acc[tm][1] + acc[tm][2] + acc[tm][3];
        #pragma unroll
        for (int r = 0; r < 4; ++r) {
            float v = rs[r];
            v += __shfl_xor(v, 1);
            v += __shfl_xor(v, 2);
            v += __shfl_xor(v, 4);
            v += __shfl_xor(v, 8);
            if (lanelo == 0)
                atomicAdd(&rowsum[growb + tm * 16 + quad * 4 + r], v);
        }
    }

    // ---- col sums: reduce over quads (xor 16, 32), then atomicAdd ----
    #pragma unroll
    for (int tn = 0; tn < 4; ++tn) {
        float cs = 0.f;
        #pragma unroll
        for (int tm = 0; tm < 8; ++tm)
            cs += acc[tm][tn][0] + acc[tm][tn][1] + acc[tm][tn][2] + acc[tm][tn][3];
        cs += __shfl_xor(cs, 16);
        cs += __shfl_xor(cs, 32);
        if (quad == 0)
            atomicAdd(&colsum[gcolb + tn * 16 + lanelo], cs);
    }
}

// ---- Kernel 3: loss = mean( 0.5*(log(rowsum)+log(colsum)) - diag ) ---------
__global__ __launch_bounds__(256)
void final_reduce(const float* __restrict__ rowsum, const float* __restrict__ colsum,
                  const float* __restrict__ diag, float* __restrict__ out, int n) {
    const int i = blockIdx.x * 256 + threadIdx.x;
    const int t = threadIdx.x;
    float v = 0.5f * (logf(rowsum[i]) + logf(colsum[i])) - diag[i];
    #pragma unroll
    for (int o = 1; o < 64; o <<= 1) v += __shfl_xor(v, o);
    __shared__ float ws[4];
    if ((t & 63) == 0) ws[t >> 6] = v;
    __syncthreads();
    if (t == 0) atomicAdd(out, (ws[0] + ws[1] + ws[2] + ws[3]) / (float)n);
}

extern "C" void kernel_launch(void* const* d_in, const int* in_sizes, int n_in,
                              void* d_out, int out_size, void* d_ws, size_t ws_size,
                              hipStream_t stream) {
    const float* img = (const float*)d_in[0];
    const float* txt = (const float*)d_in[1];
    float* out = (float*)d_out;

    const int D = 1024;
    const int N = in_sizes[0] / D;   // 8192

    unsigned char* imgq = (unsigned char*)d_ws;
    unsigned char* txtq = imgq + (size_t)N * D;
    float* rowsum = (float*)(txtq + (size_t)N * D);   // rowsum[N] ++ colsum[N]
    float* colsum = rowsum + N;
    float* diag = colsum + N;

    normalize_fp8<<<2 * N / 4, 256, 0, stream>>>(img, txt, (unsigned int*)imgq,
                                                 (unsigned int*)txtq, rowsum, out, N);

    // acc = sum of (16a)(16b) = 256*cos; scale undoes 256 and applies 1/T.
    gemm_exp_kernel<<<(N / BM) * (N / BN), 512, 0, stream>>>(
        imgq, txtq, rowsum, colsum, diag, D, 1.0f / (256.0f * 0.07f));
    final_reduce<<<N / 256, 256, 0, stream>>>(rowsum, colsum, diag, out, N);
}